// Round 15
// baseline (103.180 us; speedup 1.0000x reference)
//
#include <hip/hip_runtime.h>
#include <cstdint>

typedef unsigned short ushort_t;
typedef unsigned int uint_t;
typedef __attribute__((ext_vector_type(4))) float f32x4;
typedef __attribute__((ext_vector_type(2))) unsigned int uint2_t;
typedef __attribute__((ext_vector_type(8))) __bf16 bf16x8;

#define NB 16384
#define DK 1024   // IN + H
#define LDA_P 40  // padded A-tile leading dim (bf16 elems): 32 + 8 pad, 80B rows

#define MFMA16(a, b, c) __builtin_amdgcn_mfma_f32_16x16x32_bf16(a, b, c, 0, 0, 0)

__device__ __forceinline__ unsigned short f2b(float f) {
    unsigned u = __builtin_bit_cast(unsigned, f);
    unsigned r = u + 0x7fffu + ((u >> 16) & 1u);
    return (unsigned short)(r >> 16);
}
__device__ __forceinline__ float fast_sigmoid(float x) {
    return __fdividef(1.0f, 1.0f + __expf(-x));
}
__device__ __forceinline__ float fast_tanh(float x) {
    return __fdividef(2.0f, 1.0f + __expf(-2.0f * x)) - 1.0f;
}
// pack 2 f32 -> 2 bf16 in one u32 (RNE); no builtin on gfx950 -> inline asm
__device__ __forceinline__ uint_t cvtpk(float lo, float hi) {
    uint_t r;
    asm("v_cvt_pk_bf16_f32 %0, %1, %2" : "=v"(r) : "v"(lo), "v"(hi));
    return r;
}

__device__ __forceinline__ void gll16(const void* g, void* lds) {
    __builtin_amdgcn_global_load_lds(
        (__attribute__((address_space(1))) unsigned int*)(uintptr_t)g,
        (__attribute__((address_space(3))) unsigned int*)(unsigned int)(uintptr_t)lds,
        16, 0, 0);
}

#define BAR asm volatile("s_barrier" ::: "memory")
#define VM0 asm volatile("s_waitcnt vmcnt(0)" ::: "memory")
#define LGKM0 asm volatile("s_waitcnt lgkmcnt(0)" ::: "memory")

// ---------------- prep: W transposes (linear bf16 [n][k]) ----------------
__global__ __launch_bounds__(256) void k_transpose_w(const float* __restrict__ Wi,
                                                     const float* __restrict__ Wo,
                                                     ushort_t* __restrict__ WTI,
                                                     ushort_t* __restrict__ WTO) {
    const int z = blockIdx.z;
    if (z == 1 && blockIdx.x >= 16) return;
    const float* W = (z == 0) ? Wi : Wo;
    ushort_t* Wt = (z == 0) ? WTI : WTO;
    const int ncols = (z == 0) ? 1024 : 512;
    __shared__ float tile[32][33];
    int n0 = blockIdx.x * 32, k0 = blockIdx.y * 32;
    int tx = threadIdx.x & 31, ty = threadIdx.x >> 5;  // 32x8
#pragma unroll
    for (int i = 0; i < 32; i += 8)
        tile[ty + i][tx] = W[(size_t)(k0 + ty + i) * ncols + n0 + tx];
    __syncthreads();
#pragma unroll
    for (int i = 0; i < 32; i += 8)
        Wt[(size_t)(n0 + ty + i) * DK + k0 + tx] = f2b(tile[tx][ty + i]);
}

// ---------------- GEMM 1: lin = [x,h] @ W_in, fused gate epilogue ----------------
// A staged from f32 x/h via reg (load f32x4 -> cvt_pk -> ds_write_b64, padded tile).
// B (learn + forget panels) staged bf16 via gll16, linear. 2-phase dbuf, 2 barriers/iter.
// Block = 128 rows x 64 PAIRED cols; 4 waves; acc 64 VGPR. No k_cvt, no HN write.
__global__ __launch_bounds__(256, 2) void k_gemm1(
    const float* __restrict__ x, const float* __restrict__ h,
    const ushort_t* __restrict__ WT, const float* __restrict__ b_in,
    float* __restrict__ hnew) {
    __shared__ ushort_t Abf[2][128 * LDA_P];  // 10KB each (padded)
    __shared__ ushort_t Bs[2][2][64 * 32];    // [dbuf][L/F] 4KB each

    const int wg = blockIdx.x;                // 0..1023, XCD-pinned
    const int xcd = wg & 7, q = wg >> 3;
    const int m0 = ((xcd << 4) | (q & 15)) * 128;
    const int n0 = (q >> 4) * 64;             // paired col base in [0,512)

    const int t = threadIdx.x;
    const int lane = t & 63;
    const int wave = t >> 6;
    const int wm = wave >> 1, wn = wave & 1;  // wave tile 64 rows x 32 pairs

    f32x4 accL[4][2] = {};
    f32x4 accF[4][2] = {};

    // A f32 staging: round r (0..3): row = 32r + (t>>3), cols (t&7)*4 .. +4
    const int arow = t >> 3;        // 0..31
    const int acol = (t & 7) * 4;   // 0..28
    // B gll16 staging: row t>>2 (0..63), cols (t&3)*8
    const int brow = t >> 2;
    const int bcol = (t & 3) * 8;
    const ushort_t* gBL = WT + (size_t)(n0 + brow) * DK + bcol;
    const ushort_t* gBF = WT + (size_t)(n0 + 512 + brow) * DK + bcol;

    const int fr = lane & 15;
    const int fq = lane >> 4;
    const int kq = fq * 8;

    f32x4 areg[4];
    auto load_a = [&](int it) {   // 4 x global_load_dwordx4 (f32)
        const int kt = it * 32;
        const float* src = (kt < 512) ? (x + (size_t)m0 * 512 + kt)
                                      : (h + (size_t)m0 * 512 + (kt - 512));
#pragma unroll
        for (int r = 0; r < 4; ++r)
            areg[r] = *(const f32x4*)(src + (size_t)(32 * r + arow) * 512 + acol);
    };
    auto load_b = [&](int it, int buf) {   // 2 gll16
        const int kt = it * 32;
        gll16(gBL + kt, &Bs[buf][0][t * 8]);
        gll16(gBF + kt, &Bs[buf][1][t * 8]);
    };
    auto write_a = [&](int buf) {   // cvt + 4 x ds_write_b64 into padded tile
#pragma unroll
        for (int r = 0; r < 4; ++r) {
            uint2_t w;
            w[0] = cvtpk(areg[r][0], areg[r][1]);
            w[1] = cvtpk(areg[r][2], areg[r][3]);
            *(uint2_t*)&Abf[buf][(32 * r + arow) * LDA_P + acol] = w;
        }
    };

    float hreg[4][2][4];   // gate-h prefetch

    load_a(0);
    load_b(0, 0);
    for (int it = 0; it < 32; ++it) {
        const int cur = it & 1;
        VM0;                        // my A(it) regs + my B(it) gll16 done
        BAR;                        // all waves' B(it) staging landed
        write_a(cur);
        LGKM0;                      // my ds_writes visible
        BAR;                        // all waves' A-tile writes visible
        if (it + 1 < 32) { load_a(it + 1); load_b(it + 1, cur ^ 1); }
        if (it == 24) {             // prefetch gate-h (f32), consumed in epilogue
#pragma unroll
            for (int i = 0; i < 4; ++i)
#pragma unroll
                for (int j = 0; j < 2; ++j)
#pragma unroll
                    for (int rr = 0; rr < 4; ++rr)
                        hreg[i][j][rr] =
                            h[(size_t)(m0 + wm * 64 + i * 16 + fq * 4 + rr) * 512 +
                              n0 + wn * 32 + j * 16 + fr];
        }
        bf16x8 av[4], blv[2], bfv[2];
#pragma unroll
        for (int i = 0; i < 4; ++i)
            av[i] = *(const bf16x8*)(&Abf[cur][(wm * 64 + i * 16 + fr) * LDA_P + kq]);
#pragma unroll
        for (int j = 0; j < 2; ++j) {
            blv[j] = *(const bf16x8*)(&Bs[cur][0][(wn * 32 + j * 16 + fr) * 32 + kq]);
            bfv[j] = *(const bf16x8*)(&Bs[cur][1][(wn * 32 + j * 16 + fr) * 32 + kq]);
        }
#pragma unroll
        for (int i = 0; i < 4; ++i)
#pragma unroll
            for (int j = 0; j < 2; ++j) {
                accL[i][j] = MFMA16(av[i], blv[j], accL[i][j]);
                accF[i][j] = MFMA16(av[i], bfv[j], accF[i][j]);
            }
    }

    // epilogue: C/D map col=lane&15, row=(lane>>4)*4+reg; single f32 output
#pragma unroll
    for (int i = 0; i < 4; ++i)
#pragma unroll
        for (int j = 0; j < 2; ++j) {
            const int c = n0 + wn * 32 + j * 16 + fr;
            const float bl = b_in[c];
            const float bf = b_in[c + 512];
#pragma unroll
            for (int rr = 0; rr < 4; ++rr) {
                const int row = m0 + wm * 64 + i * 16 + fq * 4 + rr;
                float lp = accL[i][j][rr] + bl;
                float fp = accF[i][j][rr] + bf;
                float fm = fast_sigmoid(fp);
                float lr = fast_tanh(lp);
                hnew[(size_t)row * 512 + c] = lr + fm * (hreg[i][j][rr] - lr);
            }
        }
}

// ---------------- GEMM 2: out = tanh([x,h_new] @ W_out + b_out) ----------------
// A staged from f32 (x for kt<512, hnew for kt>=512) via reg-cvt; B bf16 gll16.
__global__ __launch_bounds__(256, 2) void k_gemm2(
    const float* __restrict__ x, const float* __restrict__ hnew,
    const ushort_t* __restrict__ WT, const float* __restrict__ b_out,
    float* __restrict__ out) {
    __shared__ ushort_t Abf[2][128 * LDA_P];  // 10KB each
    __shared__ ushort_t Bs[2][128 * 32];      // 8KB each

    const int wg = blockIdx.x;                // 0..511, XCD-pinned
    const int xcd = wg & 7, q = wg >> 3;
    const int m0 = ((xcd << 4) | (q & 15)) * 128;
    const int n0 = (q >> 4) * 128;

    const int t = threadIdx.x;
    const int lane = t & 63;
    const int wave = t >> 6;
    const int wm = wave >> 1, wn = wave & 1;

    f32x4 acc[4][4] = {};

    const int arow = t >> 3;        // 0..31
    const int acol = (t & 7) * 4;
    // B staging: [128][32] bf16 = 8KB -> 2 gll16: round r rows 64r + t>>2
    const int brow = t >> 2;
    const int bcol = (t & 3) * 8;
    const ushort_t* gB = WT + (size_t)n0 * DK + bcol;

    const int fr = lane & 15;
    const int fq = lane >> 4;
    const int kq = fq * 8;

    f32x4 areg[4];
    auto load_a = [&](int it) {
        const int kt = it * 32;
        const float* src = (kt < 512) ? (x + (size_t)m0 * 512 + kt)
                                      : (hnew + (size_t)m0 * 512 + (kt - 512));
#pragma unroll
        for (int r = 0; r < 4; ++r)
            areg[r] = *(const f32x4*)(src + (size_t)(32 * r + arow) * 512 + acol);
    };
    auto load_b = [&](int it, int buf) {   // 2 gll16 (rows 64r + t>>2)
        const int kt = it * 32;
#pragma unroll
        for (int r = 0; r < 2; ++r)
            gll16(gB + (size_t)(64 * r + brow) * DK + kt, &Bs[buf][64 * 32 * r + t * 8]);
    };
    auto write_a = [&](int buf) {
#pragma unroll
        for (int r = 0; r < 4; ++r) {
            uint2_t w;
            w[0] = cvtpk(areg[r][0], areg[r][1]);
            w[1] = cvtpk(areg[r][2], areg[r][3]);
            *(uint2_t*)&Abf[buf][(32 * r + arow) * LDA_P + acol] = w;
        }
    };

    load_a(0);
    load_b(0, 0);
    for (int it = 0; it < 32; ++it) {
        const int cur = it & 1;
        VM0;
        BAR;
        write_a(cur);
        LGKM0;
        BAR;
        if (it + 1 < 32) { load_a(it + 1); load_b(it + 1, cur ^ 1); }
        bf16x8 av[4], bv[4];
#pragma unroll
        for (int i = 0; i < 4; ++i) {
            av[i] = *(const bf16x8*)(&Abf[cur][(wm * 64 + i * 16 + fr) * LDA_P + kq]);
            bv[i] = *(const bf16x8*)(&Bs[cur][(wn * 64 + i * 16 + fr) * 32 + kq]);
        }
#pragma unroll
        for (int i = 0; i < 4; ++i)
#pragma unroll
            for (int j = 0; j < 4; ++j)
                acc[i][j] = MFMA16(av[i], bv[j], acc[i][j]);
    }

#pragma unroll
    for (int i = 0; i < 4; ++i)
#pragma unroll
        for (int j = 0; j < 4; ++j) {
            const int c = n0 + wn * 64 + j * 16 + fr;
            const float bo = b_out[c];
#pragma unroll
            for (int rr = 0; rr < 4; ++rr) {
                const int row = m0 + wm * 64 + i * 16 + fq * 4 + rr;
                out[(size_t)row * 512 + c] = fast_tanh(acc[i][j][rr] + bo);
            }
        }
}

extern "C" void kernel_launch(void* const* d_in, const int* in_sizes, int n_in,
                              void* d_out, int out_size, void* d_ws, size_t ws_size,
                              hipStream_t stream) {
    const float* x = (const float*)d_in[0];
    const float* h = (const float*)d_in[1];
    const float* W_in = (const float*)d_in[2];
    const float* b_in = (const float*)d_in[3];
    const float* W_out = (const float*)d_in[4];
    const float* b_out = (const float*)d_in[5];

    float* out = (float*)d_out;                    // [16384][512]
    float* hnew = out + (size_t)NB * 512;          // [16384][512]

    ushort_t* WTI = (ushort_t*)d_ws;               // [1024][1024] bf16
    ushort_t* WTO = WTI + (size_t)1024 * 1024;     // [512][1024] bf16

    k_transpose_w<<<dim3(32, 32, 2), 256, 0, stream>>>(W_in, W_out, WTI, WTO);
    k_gemm1<<<1024, 256, 0, stream>>>(x, h, WTI, b_in, hnew);
    k_gemm2<<<512, 256, 0, stream>>>(x, hnew, WTO, b_out, out);
}

// Round 16
// 85.597 us; speedup vs baseline: 1.2054x; 1.2054x over previous
//
#include <hip/hip_runtime.h>
#include <cstdint>

typedef unsigned short ushort_t;
typedef __attribute__((ext_vector_type(4))) float f32x4;
typedef __attribute__((ext_vector_type(8))) __bf16 bf16x8;
typedef __attribute__((ext_vector_type(8))) unsigned short ushort8;

#define NB 16384
#define DK 1024   // IN + H

#define MFMA16(a, b, c) __builtin_amdgcn_mfma_f32_16x16x32_bf16(a, b, c, 0, 0, 0)

__device__ __forceinline__ unsigned short f2b(float f) {
    unsigned u = __builtin_bit_cast(unsigned, f);
    unsigned r = u + 0x7fffu + ((u >> 16) & 1u);
    return (unsigned short)(r >> 16);
}
__device__ __forceinline__ float b2f(ushort_t b) {
    unsigned u = ((unsigned)b) << 16;
    return __builtin_bit_cast(float, u);
}
__device__ __forceinline__ float fast_sigmoid(float x) {
    return __fdividef(1.0f, 1.0f + __expf(-x));
}
__device__ __forceinline__ float fast_tanh(float x) {
    return __fdividef(2.0f, 1.0f + __expf(-2.0f * x)) - 1.0f;
}

__device__ __forceinline__ void gll16(const void* g, void* lds) {
    __builtin_amdgcn_global_load_lds(
        (__attribute__((address_space(1))) unsigned int*)(uintptr_t)g,
        (__attribute__((address_space(3))) unsigned int*)(unsigned int)(uintptr_t)lds,
        16, 0, 0);
}

// ---------------- prep kernels (R11, proven) ----------------
// ALL staging sources (XB, HB, HN, WT*) stored PRE-SWIZZLED (R6-verified, conflicts->0):
// within each 64-elem K-group of a row, logical elem c stored at c ^ ((row&7)<<3).

__global__ __launch_bounds__(256) void k_cvt(const float* __restrict__ x,
                                             const float* __restrict__ h,
                                             ushort_t* __restrict__ XB,
                                             ushort_t* __restrict__ HB) {
    int b = blockIdx.x;
    const float* s;
    ushort_t* d;
    if (b < 4096) { s = x; d = XB; } else { s = h; d = HB; b -= 4096; }
    size_t g = (size_t)b * 256 + threadIdx.x;
    const float* p = s + g * 8;
    f32x4 f0 = *(const f32x4*)p;
    f32x4 f1 = *(const f32x4*)(p + 4);
    ushort8 o;
#pragma unroll
    for (int j = 0; j < 4; ++j) { o[j] = f2b(f0[j]); o[j + 4] = f2b(f1[j]); }
    size_t fi = g * 8;
    int row = (int)(fi >> 9);
    int c = (int)(fi & 511);  // multiple of 8
    int swc = (c & ~63) | ((c & 63) ^ ((row & 7) << 3));
    *(ushort8*)(d + (size_t)row * 512 + swc) = o;
}

// z=0: W_in -> WTI [1024][1024] ; z=1: W_out -> WTO [512][1024]; swizzled
__global__ __launch_bounds__(256) void k_transpose_w(const float* __restrict__ Wi,
                                                     const float* __restrict__ Wo,
                                                     ushort_t* __restrict__ WTI,
                                                     ushort_t* __restrict__ WTO) {
    const int z = blockIdx.z;
    if (z == 1 && blockIdx.x >= 16) return;
    const float* W = (z == 0) ? Wi : Wo;
    ushort_t* Wt = (z == 0) ? WTI : WTO;
    const int ncols = (z == 0) ? 1024 : 512;
    __shared__ float tile[32][33];
    int n0 = blockIdx.x * 32, k0 = blockIdx.y * 32;
    int tx = threadIdx.x & 31, ty = threadIdx.x >> 5;
#pragma unroll
    for (int i = 0; i < 32; i += 8)
        tile[ty + i][tx] = W[(size_t)(k0 + ty + i) * ncols + n0 + tx];
    __syncthreads();
#pragma unroll
    for (int i = 0; i < 32; i += 8) {
        int n = n0 + ty + i;
        int k = k0 + tx;
        int kk = (k & ~63) | ((k & 63) ^ ((n & 7) << 3));
        Wt[(size_t)n * DK + kk] = f2b(tile[tx][ty + i]);
    }
}

// ---------------- GEMM 1: 8-phase, fused gate epilogue (R11, proven 52.0us) ----------------
__global__ __launch_bounds__(512, 1) void k_gemm1(
    const ushort_t* __restrict__ XB, const ushort_t* __restrict__ HB,
    const ushort_t* __restrict__ WT, const float* __restrict__ b_in,
    float* __restrict__ hnew, ushort_t* __restrict__ HN) {
    __shared__ ushort_t As[2][256 * 64];
    __shared__ ushort_t Bs[2][256 * 64];

    const int t = threadIdx.x;
    const int lane = t & 63;
    const int wid = t >> 6;
    const int wm = wid >> 2, wn = wid & 3;
    const int m0 = blockIdx.x * 256;
    const int n0p = blockIdx.y * 128;          // paired col base in [0,512)
    const int srow = t >> 3;                   // 0..63
    const int scol = (t & 7) * 8;              // 0..56
    const int fr = lane & 15, fq = lane >> 4;
    const int xr = (fr & 7) << 3;

    f32x4 acc[8][4] = {};   // [m-frag][j0,j1 learn | j2,j3 forget]

#define STA(tile, r) do { \
        int kt_ = (tile) * 64; \
        int grow_ = m0 + 64 * (r) + srow; \
        const ushort_t* s_ = (kt_ < 512) ? XB + (size_t)grow_ * 512 + kt_ + scol \
                                         : HB + (size_t)grow_ * 512 + (kt_ - 512) + scol; \
        gll16(s_, &As[(tile) & 1][(64 * (r) + srow) * 64 + scol]); \
    } while (0)
#define STB(tile, r) do { \
        int kt_ = (tile) * 64; \
        int wrow_ = ((r) < 2) ? (n0p + 64 * (r) + srow) : (512 + n0p + 64 * ((r) - 2) + srow); \
        gll16(WT + (size_t)wrow_ * DK + kt_ + scol, &Bs[(tile) & 1][(64 * (r) + srow) * 64 + scol]); \
    } while (0)

    bf16x8 a[4][2], bL[2][2], bF[2][2];

#define LDA(cb, mh) do { \
        _Pragma("unroll") for (int ii = 0; ii < 4; ++ii) \
        _Pragma("unroll") for (int kk = 0; kk < 2; ++kk) \
            a[ii][kk] = *(const bf16x8*)&As[cb][(wm * 128 + ((mh) * 4 + ii) * 16 + fr) * 64 + ((kk * 32 + fq * 8) ^ xr)]; \
    } while (0)
#define LDBL(cb) do { \
        _Pragma("unroll") for (int j = 0; j < 2; ++j) \
        _Pragma("unroll") for (int kk = 0; kk < 2; ++kk) \
            bL[j][kk] = *(const bf16x8*)&Bs[cb][(wn * 32 + j * 16 + fr) * 64 + ((kk * 32 + fq * 8) ^ xr)]; \
    } while (0)
#define LDBF(cb) do { \
        _Pragma("unroll") for (int j = 0; j < 2; ++j) \
        _Pragma("unroll") for (int kk = 0; kk < 2; ++kk) \
            bF[j][kk] = *(const bf16x8*)&Bs[cb][(128 + wn * 32 + j * 16 + fr) * 64 + ((kk * 32 + fq * 8) ^ xr)]; \
    } while (0)
#define MML(mh) do { \
        __builtin_amdgcn_s_setprio(1); \
        _Pragma("unroll") for (int kk = 0; kk < 2; ++kk) \
        _Pragma("unroll") for (int ii = 0; ii < 4; ++ii) \
        _Pragma("unroll") for (int j = 0; j < 2; ++j) \
            acc[(mh) * 4 + ii][j] = MFMA16(a[ii][kk], bL[j][kk], acc[(mh) * 4 + ii][j]); \
        __builtin_amdgcn_s_setprio(0); \
    } while (0)
#define MMF(mh) do { \
        __builtin_amdgcn_s_setprio(1); \
        _Pragma("unroll") for (int kk = 0; kk < 2; ++kk) \
        _Pragma("unroll") for (int ii = 0; ii < 4; ++ii) \
        _Pragma("unroll") for (int j = 0; j < 2; ++j) \
            acc[(mh) * 4 + ii][2 + j] = MFMA16(a[ii][kk], bF[j][kk], acc[(mh) * 4 + ii][2 + j]); \
        __builtin_amdgcn_s_setprio(0); \
    } while (0)
#define BAR asm volatile("s_barrier" ::: "memory")
#define VM2 asm volatile("s_waitcnt vmcnt(2)" ::: "memory")
#define VM0 asm volatile("s_waitcnt vmcnt(0)" ::: "memory")
#define LGKM0 do { asm volatile("s_waitcnt lgkmcnt(0)" ::: "memory"); __builtin_amdgcn_sched_barrier(0); } while (0)

    STA(0, 0); STA(0, 2);
    STA(0, 1); STA(0, 3);
    STB(0, 0); STB(0, 1);
    STB(0, 2); STB(0, 3);
    STA(1, 0); STA(1, 2);
    STA(1, 1); STA(1, 3);

    for (int i = 0; i < 8; ++i) {
        // tile 2i lives in dbuf 0 (even), tile 2i+1 in dbuf 1 — CONSTANT.
        const int g = (i < 7);
        const int t1 = 2 * i + 1, t2 = 2 * i + 2, t3 = 2 * i + 3;
        VM2; BAR;
        STB(t1, 0); STB(t1, 1);
        LDA(0, 0); LDBL(0);
        LGKM0; MML(0);
        BAR;
        if (g) { STA(t2, 0); STA(t2, 2); }
        LDBF(0);
        LGKM0; MMF(0);
        BAR;
        STB(t1, 2); STB(t1, 3);
        LDA(0, 1);
        LGKM0; MML(1);
        BAR;
        if (g) { STA(t2, 1); STA(t2, 3); }
        LGKM0; MMF(1);
        if (g) { VM2; } else { VM0; }
        BAR;
        if (g) { STB(t2, 0); STB(t2, 1); }
        LDA(1, 0); LDBL(1);
        LGKM0; MML(0);
        BAR;
        if (g) { STA(t3, 0); STA(t3, 2); }
        LDBF(1);
        LGKM0; MMF(0);
        BAR;
        if (g) { STB(t2, 2); STB(t2, 3); }
        LDA(1, 1);
        LGKM0; MML(1);
        BAR;
        if (g) { STA(t3, 1); STA(t3, 3); }
        LGKM0; MMF(1);
    }

    // fused gate epilogue: C/D map col=lane&15, row=(lane>>4)*4+reg
#pragma unroll
    for (int mf = 0; mf < 8; ++mf)
#pragma unroll
        for (int j = 0; j < 2; ++j) {
            const int cp = n0p + wn * 32 + j * 16 + fr;
            const float bl = b_in[cp];
            const float bf = b_in[cp + 512];
#pragma unroll
            for (int rr = 0; rr < 4; ++rr) {
                const int row = m0 + wm * 128 + mf * 16 + fq * 4 + rr;
                const int sc = (cp & ~63) | ((cp & 63) ^ ((row & 7) << 3));
                float lp = acc[mf][j][rr] + bl;
                float fp = acc[mf][2 + j][rr] + bf;
                float hv = b2f(HB[(size_t)row * 512 + sc]);
                float fm = fast_sigmoid(fp);
                float lr = fast_tanh(lp);
                float hn = lr + fm * (hv - lr);
                hnew[(size_t)row * 512 + cp] = hn;
                HN[(size_t)row * 512 + sc] = f2b(hn);
            }
        }
}

// ---------------- GEMM 2: NEW 4-phase counted-vmcnt 256x128 ----------------
// BM=256, BN=128, BK=64; 8 waves (2m x 4n), wave tile 128x32; acc 8x2 f32x4.
// Ledger (issue order): prologue {B0:2, A0:4, B1:2}; iter i: ph0 stages A(2i+1)x4,
// ph1 B(2i+2)x2, ph2 A(2i+2)x4, ph3 B(2i+3)x2. Waits: ph0 VM2 (always);
// ph2 VM2 (i<7) / VM0 (i=7). dbuf = tile parity (constant). Sources pre-swizzled.
__global__ __launch_bounds__(512, 1) void k_gemm2(
    const ushort_t* __restrict__ XB, const ushort_t* __restrict__ HN,
    const ushort_t* __restrict__ WT, const float* __restrict__ b_out,
    float* __restrict__ out) {
    __shared__ ushort_t A2[2][256 * 64];   // 64KB
    __shared__ ushort_t B2[2][128 * 64];   // 32KB

    const int t = threadIdx.x;
    const int lane = t & 63;
    const int wid = t >> 6;
    const int wm = wid >> 2, wn = wid & 3;
    const int m0 = blockIdx.x * 256;
    const int n0 = blockIdx.y * 128;
    const int srow = t >> 3;
    const int scol = (t & 7) * 8;
    const int fr = lane & 15, fq = lane >> 4;
    const int xr = (fr & 7) << 3;

    f32x4 acc[8][2] = {};

#define STA2(tile, r) do { \
        int kt_ = (tile) * 64; \
        int grow_ = m0 + 64 * (r) + srow; \
        const ushort_t* s_ = (kt_ < 512) ? XB + (size_t)grow_ * 512 + kt_ + scol \
                                         : HN + (size_t)grow_ * 512 + (kt_ - 512) + scol; \
        gll16(s_, &A2[(tile) & 1][(64 * (r) + srow) * 64 + scol]); \
    } while (0)
#define STB2(tile, r) do { \
        int kt_ = (tile) * 64; \
        gll16(WT + (size_t)(n0 + 64 * (r) + srow) * DK + kt_ + scol, \
              &B2[(tile) & 1][(64 * (r) + srow) * 64 + scol]); \
    } while (0)

    bf16x8 a2[4][2], b2[2][2];

#define LDA2(cb, mh) do { \
        _Pragma("unroll") for (int ii = 0; ii < 4; ++ii) \
        _Pragma("unroll") for (int kk = 0; kk < 2; ++kk) \
            a2[ii][kk] = *(const bf16x8*)&A2[cb][(wm * 128 + ((mh) * 4 + ii) * 16 + fr) * 64 + ((kk * 32 + fq * 8) ^ xr)]; \
    } while (0)
#define LDB2(cb) do { \
        _Pragma("unroll") for (int j = 0; j < 2; ++j) \
        _Pragma("unroll") for (int kk = 0; kk < 2; ++kk) \
            b2[j][kk] = *(const bf16x8*)&B2[cb][(wn * 32 + j * 16 + fr) * 64 + ((kk * 32 + fq * 8) ^ xr)]; \
    } while (0)
#define MM2(mh) do { \
        __builtin_amdgcn_s_setprio(1); \
        _Pragma("unroll") for (int kk = 0; kk < 2; ++kk) \
        _Pragma("unroll") for (int ii = 0; ii < 4; ++ii) \
        _Pragma("unroll") for (int j = 0; j < 2; ++j) \
            acc[(mh) * 4 + ii][j] = MFMA16(a2[ii][kk], b2[j][kk], acc[(mh) * 4 + ii][j]); \
        __builtin_amdgcn_s_setprio(0); \
    } while (0)

    // prologue: B(0)x2, A(0)x4, B(1)x2  -> 8 outstanding
    STB2(0, 0); STB2(0, 1);
    STA2(0, 0); STA2(0, 1); STA2(0, 2); STA2(0, 3);
    STB2(1, 0); STB2(1, 1);

    for (int i = 0; i < 8; ++i) {
        const int g = (i < 7);
        const int t1 = 2 * i + 1, t2 = 2 * i + 2, t3 = 2 * i + 3;
        // ph0: tile 2i (dbuf0), mh0 x both j ; stage A(t1) -> dbuf1
        VM2; BAR;
        STA2(t1, 0); STA2(t1, 1); STA2(t1, 2); STA2(t1, 3);
        LDA2(0, 0); LDB2(0);
        LGKM0; MM2(0);
        // ph1: mh1 ; stage B(t2) -> dbuf0 (B0 reads done ph0)
        BAR;
        if (g) { STB2(t2, 0); STB2(t2, 1); }
        LDA2(0, 1);
        LGKM0; MM2(1);
        // ph2: tile 2i+1 (dbuf1), mh0 ; stage A(t2) -> dbuf0 (A0 reads done ph1)
        if (g) { VM2; } else { VM0; }
        BAR;
        if (g) { STA2(t2, 0); STA2(t2, 1); STA2(t2, 2); STA2(t2, 3); }
        LDA2(1, 0); LDB2(1);
        LGKM0; MM2(0);
        // ph3: mh1 ; stage B(t3) -> dbuf1 (B1 reads done ph2)
        BAR;
        if (g) { STB2(t3, 0); STB2(t3, 1); }
        LDA2(1, 1);
        LGKM0; MM2(1);
    }

    // epilogue
#pragma unroll
    for (int mf = 0; mf < 8; ++mf)
#pragma unroll
        for (int j = 0; j < 2; ++j) {
            const int c = n0 + wn * 32 + j * 16 + fr;
            const float bo = b_out[c];
#pragma unroll
            for (int rr = 0; rr < 4; ++rr) {
                const int row = m0 + wm * 128 + mf * 16 + fq * 4 + rr;
                out[(size_t)row * 512 + c] = fast_tanh(acc[mf][j][rr] + bo);
            }
        }
}

extern "C" void kernel_launch(void* const* d_in, const int* in_sizes, int n_in,
                              void* d_out, int out_size, void* d_ws, size_t ws_size,
                              hipStream_t stream) {
    const float* x = (const float*)d_in[0];
    const float* h = (const float*)d_in[1];
    const float* W_in = (const float*)d_in[2];
    const float* b_in = (const float*)d_in[3];
    const float* W_out = (const float*)d_in[4];
    const float* b_out = (const float*)d_in[5];

    float* out = (float*)d_out;                    // [16384][512]
    float* hnew = out + (size_t)NB * 512;          // [16384][512]

    ushort_t* XB = (ushort_t*)d_ws;
    ushort_t* HB = XB + (size_t)NB * 512;
    ushort_t* HN = HB + (size_t)NB * 512;
    ushort_t* WTI = HN + (size_t)NB * 512;
    ushort_t* WTO = WTI + (size_t)1024 * 1024;

    k_cvt<<<8192, 256, 0, stream>>>(x, h, XB, HB);
    k_transpose_w<<<dim3(32, 32, 2), 256, 0, stream>>>(W_in, W_out, WTI, WTO);
    k_gemm1<<<dim3(64, 4), 512, 0, stream>>>(XB, HB, WTI, b_in, hnew, HN);
    k_gemm2<<<dim3(64, 4), 512, 0, stream>>>(XB, HN, WTO, b_out, out);
}